// Round 1
// baseline (1029.994 us; speedup 1.0000x reference)
//
#include <hip/hip_runtime.h>
#include <hip/hip_bf16.h>
#include <cstdint>

#define HID 128

static inline size_t align_up(size_t x, size_t a) { return (x + a - 1) & ~(a - 1); }

// ---------------------------------------------------------------------------
// Edge dtype sniffer: int64 edge data with values < 2^31 has all odd 32-bit
// words == 0. Random int32 indices in [0,100000) make that probability ~0.
// ---------------------------------------------------------------------------
__global__ void detect_i64_kernel(const unsigned int* __restrict__ p, int nwords,
                                  int* __restrict__ flag) {
  __shared__ int any;
  if (threadIdx.x == 0) any = 0;
  __syncthreads();
  for (int i = threadIdx.x; i < 1024; i += blockDim.x) {
    int w = 2 * i + 1;
    if (w < nwords && p[w] != 0u) atomicOr(&any, 1);
  }
  __syncthreads();
  if (threadIdx.x == 0) *flag = (any == 0) ? 1 : 0;
}

__global__ void extract_kernel(const void* __restrict__ ei, const int* __restrict__ flag,
                               int E, int* __restrict__ src32, int* __restrict__ dst32) {
  int e = blockIdx.x * blockDim.x + threadIdx.x;
  if (e >= E) return;
  if (*flag) {
    const long long* p = (const long long*)ei;
    src32[e] = (int)p[e];
    dst32[e] = (int)p[(size_t)E + e];
  } else {
    const int* p = (const int*)ei;
    src32[e] = p[e];
    dst32[e] = p[(size_t)E + e];
  }
}

__global__ void count_kernel(const int* __restrict__ dst32, int* __restrict__ cnt, int E) {
  int e = blockIdx.x * blockDim.x + threadIdx.x;
  if (e >= E) return;
  atomicAdd(&cnt[dst32[e]], 1);
}

__global__ void dinv_kernel(const int* __restrict__ cnt, float* __restrict__ dinv, int N) {
  int i = blockIdx.x * blockDim.x + threadIdx.x;
  if (i >= N) return;
  // deg includes the self-loop -> always >= 1
  dinv[i] = rsqrtf((float)(cnt[i] + 1));
}

__global__ void norm_kernel(const int* __restrict__ src32, const int* __restrict__ dst32,
                            const float* __restrict__ dinv, float* __restrict__ normv, int E) {
  int e = blockIdx.x * blockDim.x + threadIdx.x;
  if (e >= E) return;
  normv[e] = dinv[src32[e]] * dinv[dst32[e]];
}

// ---------------------------------------------------------------------------
// Two-level exclusive scan over per-node counts -> CSR row offsets.
// ---------------------------------------------------------------------------
__global__ __launch_bounds__(1024) void scan_local_kernel(const int* __restrict__ cnt,
    int* __restrict__ off, int* __restrict__ bsum, int N) {
  __shared__ int buf[1024];
  int tid = threadIdx.x;
  int i = blockIdx.x * 1024 + tid;
  int v = (i < N) ? cnt[i] : 0;
  buf[tid] = v;
  __syncthreads();
  #pragma unroll
  for (int s = 1; s < 1024; s <<= 1) {
    int t = (tid >= s) ? buf[tid - s] : 0;
    __syncthreads();
    buf[tid] += t;
    __syncthreads();
  }
  if (i < N) off[i] = buf[tid] - v;  // local exclusive
  if (tid == 1023) bsum[blockIdx.x] = buf[1023];
}

__global__ __launch_bounds__(128) void scan_bsum_kernel(const int* __restrict__ bsum, int nb,
    int* __restrict__ boff, int* __restrict__ offN) {
  __shared__ int b[128];
  int tid = threadIdx.x;
  int v = (tid < nb) ? bsum[tid] : 0;
  b[tid] = v;
  __syncthreads();
  #pragma unroll
  for (int s = 1; s < 128; s <<= 1) {
    int t = (tid >= s) ? b[tid - s] : 0;
    __syncthreads();
    b[tid] += t;
    __syncthreads();
  }
  if (tid < nb) boff[tid] = b[tid] - v;  // exclusive block offsets
  if (tid == 127) *offN = b[127];        // grand total = E
}

__global__ void scan_add_kernel(int* __restrict__ off, const int* __restrict__ boff,
                                int* __restrict__ cursor, int N) {
  int i = blockIdx.x * blockDim.x + threadIdx.x;
  if (i >= N) return;
  int o = off[i] + boff[i >> 10];
  off[i] = o;
  cursor[i] = o;
}

__global__ void fill_kernel(const int* __restrict__ src32, const int* __restrict__ dst32,
                            const float* __restrict__ normv, int* __restrict__ cursor,
                            int* __restrict__ csr_src, float* __restrict__ csr_norm, int E) {
  int e = blockIdx.x * blockDim.x + threadIdx.x;
  if (e >= E) return;
  int d = dst32[e];
  int pos = atomicAdd(&cursor[d], 1);
  csr_src[pos] = src32[e];
  csr_norm[pos] = normv[e];
}

// ---------------------------------------------------------------------------
// f32 GEMM: out[M,128] = A[M,K] @ W[K,128] (+bias, relu).
// Block = 64 rows x 128 cols, 256 threads; per thread 8 rows x 4 cols.
// x-tile staged in LDS (stride 36 to spread banks); W rows read from L2.
// ---------------------------------------------------------------------------
template <int K, bool BIAS_RELU>
__global__ __launch_bounds__(256) void gemm_kernel(const float* __restrict__ A,
    const float* __restrict__ W, const float* __restrict__ bias,
    float* __restrict__ out, int M) {
  __shared__ float xs[64 * 36];
  const int tid = threadIdx.x;
  const int cg = tid & 31;   // column group -> cols cg*4 .. cg*4+3
  const int rg = tid >> 5;   // row group   -> rows rg*8 .. rg*8+7
  const int R = blockIdx.x * 64;
  float acc[8][4];
  #pragma unroll
  for (int i = 0; i < 8; ++i) acc[i][0] = acc[i][1] = acc[i][2] = acc[i][3] = 0.f;

  const int lrow = tid >> 2;        // 0..63
  const int lkk = (tid & 3) * 8;    // 0,8,16,24

  for (int k0 = 0; k0 < K; k0 += 32) {
    float4 v0 = {0, 0, 0, 0}, v1 = {0, 0, 0, 0};
    int r = R + lrow;
    if (r < M) {
      const float* src = &A[(size_t)r * K + k0 + lkk];
      v0 = *(const float4*)src;
      v1 = *(const float4*)(src + 4);
    }
    __syncthreads();
    *(float4*)&xs[lrow * 36 + lkk] = v0;
    *(float4*)&xs[lrow * 36 + lkk + 4] = v1;
    __syncthreads();
    #pragma unroll
    for (int kk = 0; kk < 32; ++kk) {
      float4 w = *(const float4*)&W[(size_t)(k0 + kk) * 128 + cg * 4];
      #pragma unroll
      for (int i = 0; i < 8; ++i) {
        float xv = xs[(rg * 8 + i) * 36 + kk];
        acc[i][0] = fmaf(xv, w.x, acc[i][0]);
        acc[i][1] = fmaf(xv, w.y, acc[i][1]);
        acc[i][2] = fmaf(xv, w.z, acc[i][2]);
        acc[i][3] = fmaf(xv, w.w, acc[i][3]);
      }
    }
  }

  float4 bv = {0, 0, 0, 0};
  if constexpr (BIAS_RELU) bv = *(const float4*)&bias[cg * 4];
  #pragma unroll
  for (int i = 0; i < 8; ++i) {
    int r = R + rg * 8 + i;
    if (r < M) {
      float4 v;
      v.x = acc[i][0]; v.y = acc[i][1]; v.z = acc[i][2]; v.w = acc[i][3];
      if constexpr (BIAS_RELU) {
        v.x = fmaxf(v.x + bv.x, 0.f);
        v.y = fmaxf(v.y + bv.y, 0.f);
        v.z = fmaxf(v.z + bv.z, 0.f);
        v.w = fmaxf(v.w + bv.w, 0.f);
      }
      *(float4*)&out[(size_t)r * 128 + cg * 4] = v;
    }
  }
}

// ---------------------------------------------------------------------------
// Aggregation: one wave per node. out[n] = relu(sum_{e: dst=n} norm_e*hw[src_e]
//                                              + dinv[n]^2*hw[n] + bias)
// Lane l covers feature columns [2l, 2l+1] (float2 -> 512B coalesced gather).
// ---------------------------------------------------------------------------
__global__ __launch_bounds__(256) void aggregate_kernel(const float* __restrict__ hw,
    const int* __restrict__ off, const int* __restrict__ csr_src,
    const float* __restrict__ csr_norm, const float* __restrict__ dinv,
    const float* __restrict__ bias, float* __restrict__ out, int N) {
  int wid = (blockIdx.x * blockDim.x + threadIdx.x) >> 6;
  int lane = threadIdx.x & 63;
  if (wid >= N) return;
  const float2* hw2 = (const float2*)hw;
  int beg = off[wid], end = off[wid + 1];
  float ax = 0.f, ay = 0.f;
  for (int j = beg; j < end; ++j) {
    int s = csr_src[j];
    float nm = csr_norm[j];
    float2 v = hw2[(size_t)s * 64 + lane];
    ax = fmaf(nm, v.x, ax);
    ay = fmaf(nm, v.y, ay);
  }
  float di = dinv[wid];
  float snm = di * di;
  float2 v = hw2[(size_t)wid * 64 + lane];
  ax = fmaf(snm, v.x, ax);
  ay = fmaf(snm, v.y, ay);
  float2 b = ((const float2*)bias)[lane];
  ax = fmaxf(ax + b.x, 0.f);
  ay = fmaxf(ay + b.y, 0.f);
  float2 o; o.x = ax; o.y = ay;
  ((float2*)out)[(size_t)wid * 64 + lane] = o;
}

// ---------------------------------------------------------------------------
// Final: logits = h @ W2 + b2 ; out = log_softmax(logits). One wave per row,
// lanes 0..39 each own one output class.
// ---------------------------------------------------------------------------
__global__ __launch_bounds__(256) void final_kernel(const float* __restrict__ h,
    const float* __restrict__ W2, const float* __restrict__ b2,
    float* __restrict__ out, int N) {
  int wid = (blockIdx.x * blockDim.x + threadIdx.x) >> 6;
  int lane = threadIdx.x & 63;
  if (wid >= N) return;
  const float* hr = &h[(size_t)wid * 128];
  float logit = -1e30f;
  if (lane < 40) {
    float s = b2[lane];
    #pragma unroll 4
    for (int k = 0; k < 128; ++k) s = fmaf(hr[k], W2[k * 40 + lane], s);
    logit = s;
  }
  float m = logit;
  #pragma unroll
  for (int sh = 32; sh > 0; sh >>= 1) m = fmaxf(m, __shfl_xor(m, sh));
  float e = (lane < 40) ? expf(logit - m) : 0.f;
  float sum = e;
  #pragma unroll
  for (int sh = 32; sh > 0; sh >>= 1) sum += __shfl_xor(sum, sh);
  if (lane < 40) out[(size_t)wid * 40 + lane] = logit - m - logf(sum);
}

// ---------------------------------------------------------------------------
extern "C" void kernel_launch(void* const* d_in, const int* in_sizes, int n_in,
                              void* d_out, int out_size, void* d_ws, size_t ws_size,
                              hipStream_t stream) {
  const float* x   = (const float*)d_in[0];
  const void*  ei  = d_in[1];
  const float* W1  = (const float*)d_in[2];
  const float* b1  = (const float*)d_in[3];
  const float* Wg0 = (const float*)d_in[4];
  const float* bg0 = (const float*)d_in[5];
  const float* Wg1 = (const float*)d_in[6];
  const float* bg1 = (const float*)d_in[7];
  const float* W2  = (const float*)d_in[8];
  const float* b2  = (const float*)d_in[9];
  float* out = (float*)d_out;

  const int N = in_sizes[0] / 512;
  const int E = in_sizes[1] / 2;

  char* wsb = (char*)d_ws;
  size_t o = 0;
  auto alloc = [&](size_t bytes) -> void* {
    void* p = wsb + o;
    o = align_up(o + bytes, 256);
    return p;
  };
  int*   flag    = (int*)alloc(4);
  int*   src32   = (int*)alloc((size_t)E * 4);
  int*   dst32   = (int*)alloc((size_t)E * 4);
  float* normv   = (float*)alloc((size_t)E * 4);
  int*   cnt     = (int*)alloc((size_t)N * 4);
  float* dinv    = (float*)alloc((size_t)N * 4);
  int*   off     = (int*)alloc((size_t)(N + 1) * 4);
  int*   cursor  = (int*)alloc((size_t)N * 4);
  int*   bsum    = (int*)alloc(128 * 4);
  int*   boff    = (int*)alloc(128 * 4);
  int*   csr_src = (int*)alloc((size_t)E * 4);
  float* csr_nrm = (float*)alloc((size_t)E * 4);
  float* bufA    = (float*)alloc((size_t)N * HID * 4);
  float* bufB    = (float*)alloc((size_t)N * HID * 4);
  (void)ws_size; (void)n_in; (void)out_size;

  const int tpb = 256;
  const int ebl = (E + tpb - 1) / tpb;
  const int nbl = (N + tpb - 1) / tpb;

  // --- graph prep: extract edges, degrees, norm, CSR ---
  detect_i64_kernel<<<1, 256, 0, stream>>>((const unsigned int*)ei, 2 * E, flag);
  extract_kernel<<<ebl, tpb, 0, stream>>>(ei, flag, E, src32, dst32);
  hipMemsetAsync(cnt, 0, (size_t)N * 4, stream);
  count_kernel<<<ebl, tpb, 0, stream>>>(dst32, cnt, E);
  dinv_kernel<<<nbl, tpb, 0, stream>>>(cnt, dinv, N);
  norm_kernel<<<ebl, tpb, 0, stream>>>(src32, dst32, dinv, normv, E);
  const int nsb = (N + 1023) / 1024;
  scan_local_kernel<<<nsb, 1024, 0, stream>>>(cnt, off, bsum, N);
  scan_bsum_kernel<<<1, 128, 0, stream>>>(bsum, nsb, boff, off + N);
  scan_add_kernel<<<nbl, tpb, 0, stream>>>(off, boff, cursor, N);
  fill_kernel<<<ebl, tpb, 0, stream>>>(src32, dst32, normv, cursor, csr_src, csr_nrm, E);

  // --- network ---
  const int gbl = (N + 63) / 64;
  const int abl = (N * 64 + tpb - 1) / tpb;  // one wave per node

  gemm_kernel<512, true><<<gbl, 256, 0, stream>>>(x, W1, b1, bufA, N);

  gemm_kernel<128, false><<<gbl, 256, 0, stream>>>(bufA, Wg0, nullptr, bufB, N);
  aggregate_kernel<<<abl, tpb, 0, stream>>>(bufB, off, csr_src, csr_nrm, dinv, bg0, bufA, N);

  gemm_kernel<128, false><<<gbl, 256, 0, stream>>>(bufA, Wg1, nullptr, bufB, N);
  aggregate_kernel<<<abl, tpb, 0, stream>>>(bufB, off, csr_src, csr_nrm, dinv, bg1, bufA, N);

  final_kernel<<<abl, tpb, 0, stream>>>(bufA, W2, b2, out, N);
}

// Round 3
// 820.023 us; speedup vs baseline: 1.2561x; 1.2561x over previous
//
#include <hip/hip_runtime.h>
#include <hip/hip_bf16.h>
#include <cstdint>

#define HID 128

typedef short s16x8 __attribute__((ext_vector_type(8)));
typedef float f32x4 __attribute__((ext_vector_type(4)));

static inline size_t align_up(size_t x, size_t a) { return (x + a - 1) & ~(a - 1); }

__device__ inline ushort f2bf(float f) {
  uint u = __float_as_uint(f);
  u += 0x7FFFu + ((u >> 16) & 1u);
  return (ushort)(u >> 16);
}

// ---------------------------------------------------------------------------
// Edge dtype sniffer: int64 edge data with values < 2^31 has all odd 32-bit
// words == 0.
// ---------------------------------------------------------------------------
__global__ void detect_i64_kernel(const unsigned int* __restrict__ p, int nwords,
                                  int* __restrict__ flag) {
  __shared__ int any;
  if (threadIdx.x == 0) any = 0;
  __syncthreads();
  for (int i = threadIdx.x; i < 1024; i += blockDim.x) {
    int w = 2 * i + 1;
    if (w < nwords && p[w] != 0u) atomicOr(&any, 1);
  }
  __syncthreads();
  if (threadIdx.x == 0) *flag = (any == 0) ? 1 : 0;
}

__global__ void extract_kernel(const void* __restrict__ ei, const int* __restrict__ flag,
                               int E, int* __restrict__ src32, int* __restrict__ dst32) {
  int e = blockIdx.x * blockDim.x + threadIdx.x;
  if (e >= E) return;
  if (*flag) {
    const long long* p = (const long long*)ei;
    src32[e] = (int)p[e];
    dst32[e] = (int)p[(size_t)E + e];
  } else {
    const int* p = (const int*)ei;
    src32[e] = p[e];
    dst32[e] = p[(size_t)E + e];
  }
}

__global__ void count_kernel(const int* __restrict__ dst32, int* __restrict__ cnt, int E) {
  int e = blockIdx.x * blockDim.x + threadIdx.x;
  if (e >= E) return;
  atomicAdd(&cnt[dst32[e]], 1);
}

__global__ void dinv_kernel(const int* __restrict__ cnt, float* __restrict__ dinv, int N) {
  int i = blockIdx.x * blockDim.x + threadIdx.x;
  if (i >= N) return;
  dinv[i] = rsqrtf((float)(cnt[i] + 1));
}

__global__ void norm_kernel(const int* __restrict__ src32, const int* __restrict__ dst32,
                            const float* __restrict__ dinv, float* __restrict__ normv, int E) {
  int e = blockIdx.x * blockDim.x + threadIdx.x;
  if (e >= E) return;
  normv[e] = dinv[src32[e]] * dinv[dst32[e]];
}

// ---------------------------------------------------------------------------
// Two-level exclusive scan over per-node counts -> CSR row offsets.
// ---------------------------------------------------------------------------
__global__ __launch_bounds__(1024) void scan_local_kernel(const int* __restrict__ cnt,
    int* __restrict__ off, int* __restrict__ bsum, int N) {
  __shared__ int buf[1024];
  int tid = threadIdx.x;
  int i = blockIdx.x * 1024 + tid;
  int v = (i < N) ? cnt[i] : 0;
  buf[tid] = v;
  __syncthreads();
  #pragma unroll
  for (int s = 1; s < 1024; s <<= 1) {
    int t = (tid >= s) ? buf[tid - s] : 0;
    __syncthreads();
    buf[tid] += t;
    __syncthreads();
  }
  if (i < N) off[i] = buf[tid] - v;
  if (tid == 1023) bsum[blockIdx.x] = buf[1023];
}

__global__ __launch_bounds__(128) void scan_bsum_kernel(const int* __restrict__ bsum, int nb,
    int* __restrict__ boff, int* __restrict__ offN) {
  __shared__ int b[128];
  int tid = threadIdx.x;
  int v = (tid < nb) ? bsum[tid] : 0;
  b[tid] = v;
  __syncthreads();
  #pragma unroll
  for (int s = 1; s < 128; s <<= 1) {
    int t = (tid >= s) ? b[tid - s] : 0;
    __syncthreads();
    b[tid] += t;
    __syncthreads();
  }
  if (tid < nb) boff[tid] = b[tid] - v;
  if (tid == 127) *offN = b[127];
}

__global__ void scan_add_kernel(int* __restrict__ off, const int* __restrict__ boff,
                                int* __restrict__ cursor, int N) {
  int i = blockIdx.x * blockDim.x + threadIdx.x;
  if (i >= N) return;
  int o = off[i] + boff[i >> 10];
  off[i] = o;
  cursor[i] = o;
}

__global__ void fill_kernel(const int* __restrict__ src32, const int* __restrict__ dst32,
                            const float* __restrict__ normv, int* __restrict__ cursor,
                            int* __restrict__ csr_src, float* __restrict__ csr_norm, int E) {
  int e = blockIdx.x * blockDim.x + threadIdx.x;
  if (e >= E) return;
  int d = dst32[e];
  int pos = atomicAdd(&cursor[d], 1);
  csr_src[pos] = src32[e];
  csr_norm[pos] = normv[e];
}

// ---------------------------------------------------------------------------
// Weight transpose + bf16 convert: W[K][128] f32 -> Wt[128][K] bf16.
// ---------------------------------------------------------------------------
__global__ void convert_w_kernel(const float* __restrict__ W, ushort* __restrict__ Wt, int K) {
  int id = blockIdx.x * blockDim.x + threadIdx.x;
  if (id >= K * 128) return;
  int c = id & 127;
  int k = id >> 7;
  Wt[(size_t)c * K + k] = f2bf(W[id]);
}

// ---------------------------------------------------------------------------
// MFMA GEMM: out[M,128] = A[M,K](f32) @ W[K,128] (Wt pre-transposed bf16).
// Block: 256 threads = 4 waves, 64 rows x 128 cols tile. Wave w owns rows
// 16w..16w+15, 8 MFMA(16x16x32) col-tiles.
// LDS: row stride 40 ushorts (32 data + 8 pad) -> no swizzle needed; rows at
// 80B stride give 8 distinct 16B positions mod 128B -> 2-way access = free.
// (Round-2 bug: XOR key (row&7)<<3 was 3 bits on a 2-bit granule index ->
//  writes spilled into neighboring rows. Pad instead.)
// A/B fragments packed with identical granule->k map (granule g = k 8g..8g+7),
// so HW pairs them consistently. C/D: col=lane&15, row=(lane>>4)*4+reg.
// ---------------------------------------------------------------------------
#define LDSTR 40
template <int K, bool BIAS_RELU>
__global__ __launch_bounds__(256) void gemm_mfma_kernel(const float* __restrict__ A,
    const ushort* __restrict__ Wt, const float* __restrict__ bias,
    void* __restrict__ outp, int M) {
  __shared__ __align__(16) ushort lA[64 * LDSTR];
  __shared__ __align__(16) ushort lB[128 * LDSTR];
  const int tid = threadIdx.x;
  const int w = tid >> 6;
  const int l = tid & 63;
  const int l15 = l & 15;
  const int kg = l >> 4;
  const int R = blockIdx.x * 64;

  f32x4 acc[8];
  #pragma unroll
  for (int c = 0; c < 8; ++c) acc[c] = f32x4{0.f, 0.f, 0.f, 0.f};

  // staging assignments
  const int ar = tid >> 2;              // A row 0..63
  const int ag = tid & 3;               // A granule 0..3
  const int bc = tid >> 1;              // B col 0..127
  const int bh = tid & 1;               // B half -> granules 2bh, 2bh+1
  const int aIdx = ar * LDSTR + ag * 8;
  const int bIdx0 = bc * LDSTR + bh * 16;
  const int bIdx1 = bIdx0 + 8;
  const int arow = R + ar;

  const int aRd = (16 * w + l15) * LDSTR + kg * 8;

  for (int k0 = 0; k0 < K; k0 += 32) {
    float4 v0 = {0, 0, 0, 0}, v1 = {0, 0, 0, 0};
    if (arow < M) {
      const float* s = &A[(size_t)arow * K + k0 + ag * 8];
      v0 = *(const float4*)s;
      v1 = *(const float4*)(s + 4);
    }
    s16x8 wb0 = *(const s16x8*)&Wt[(size_t)bc * K + k0 + bh * 16];
    s16x8 wb1 = *(const s16x8*)&Wt[(size_t)bc * K + k0 + bh * 16 + 8];
    __syncthreads();
    s16x8 pa;
    pa[0] = (short)f2bf(v0.x); pa[1] = (short)f2bf(v0.y);
    pa[2] = (short)f2bf(v0.z); pa[3] = (short)f2bf(v0.w);
    pa[4] = (short)f2bf(v1.x); pa[5] = (short)f2bf(v1.y);
    pa[6] = (short)f2bf(v1.z); pa[7] = (short)f2bf(v1.w);
    *(s16x8*)&lA[aIdx] = pa;
    *(s16x8*)&lB[bIdx0] = wb0;
    *(s16x8*)&lB[bIdx1] = wb1;
    __syncthreads();
    s16x8 af = *(const s16x8*)&lA[aRd];
    #pragma unroll
    for (int c = 0; c < 8; ++c) {
      s16x8 bfr = *(const s16x8*)&lB[(16 * c + l15) * LDSTR + kg * 8];
      acc[c] = __builtin_amdgcn_mfma_f32_16x16x32_bf16(af, bfr, acc[c], 0, 0, 0);
    }
  }

  #pragma unroll
  for (int c = 0; c < 8; ++c) {
    #pragma unroll
    for (int v = 0; v < 4; ++v) {
      int row = R + 16 * w + kg * 4 + v;
      int col = 16 * c + l15;
      if (row < M) {
        float val = acc[c][v];
        if constexpr (BIAS_RELU) {
          val = fmaxf(val + bias[col], 0.f);
          ((float*)outp)[(size_t)row * 128 + col] = val;
        } else {
          ((ushort*)outp)[(size_t)row * 128 + col] = f2bf(val);
        }
      }
    }
  }
}

// ---------------------------------------------------------------------------
// Aggregation over bf16 hw: one wave per node; lane l covers cols 2l,2l+1
// (one dword gather per edge per lane). f32 accumulate; self-loop+bias+ReLU.
// ---------------------------------------------------------------------------
__global__ __launch_bounds__(256) void aggregate_bf16_kernel(const ushort* __restrict__ hw,
    const int* __restrict__ off, const int* __restrict__ csr_src,
    const float* __restrict__ csr_norm, const float* __restrict__ dinv,
    const float* __restrict__ bias, float* __restrict__ out, int N) {
  int wid = (blockIdx.x * blockDim.x + threadIdx.x) >> 6;
  int lane = threadIdx.x & 63;
  if (wid >= N) return;
  const uint* hw4 = (const uint*)hw;
  int beg = off[wid], end = off[wid + 1];
  float ax = 0.f, ay = 0.f;
  for (int j = beg; j < end; ++j) {
    int s = csr_src[j];
    float nm = csr_norm[j];
    uint v = hw4[(size_t)s * 64 + lane];
    ax = fmaf(nm, __uint_as_float(v << 16), ax);
    ay = fmaf(nm, __uint_as_float(v & 0xFFFF0000u), ay);
  }
  float di = dinv[wid];
  float snm = di * di;
  uint v = hw4[(size_t)wid * 64 + lane];
  ax = fmaf(snm, __uint_as_float(v << 16), ax);
  ay = fmaf(snm, __uint_as_float(v & 0xFFFF0000u), ay);
  float2 b = ((const float2*)bias)[lane];
  float2 o;
  o.x = fmaxf(ax + b.x, 0.f);
  o.y = fmaxf(ay + b.y, 0.f);
  ((float2*)out)[(size_t)wid * 64 + lane] = o;
}

// ---------------------------------------------------------------------------
// Final: logits = h @ W2 + b2 ; out = log_softmax. One wave per row.
// ---------------------------------------------------------------------------
__global__ __launch_bounds__(256) void final_kernel(const float* __restrict__ h,
    const float* __restrict__ W2, const float* __restrict__ b2,
    float* __restrict__ out, int N) {
  int wid = (blockIdx.x * blockDim.x + threadIdx.x) >> 6;
  int lane = threadIdx.x & 63;
  if (wid >= N) return;
  const float* hr = &h[(size_t)wid * 128];
  float logit = -1e30f;
  if (lane < 40) {
    float s = b2[lane];
    #pragma unroll 4
    for (int k = 0; k < 128; ++k) s = fmaf(hr[k], W2[k * 40 + lane], s);
    logit = s;
  }
  float m = logit;
  #pragma unroll
  for (int sh = 32; sh > 0; sh >>= 1) m = fmaxf(m, __shfl_xor(m, sh));
  float e = (lane < 40) ? expf(logit - m) : 0.f;
  float sum = e;
  #pragma unroll
  for (int sh = 32; sh > 0; sh >>= 1) sum += __shfl_xor(sum, sh);
  if (lane < 40) out[(size_t)wid * 40 + lane] = logit - m - logf(sum);
}

// ---------------------------------------------------------------------------
extern "C" void kernel_launch(void* const* d_in, const int* in_sizes, int n_in,
                              void* d_out, int out_size, void* d_ws, size_t ws_size,
                              hipStream_t stream) {
  const float* x   = (const float*)d_in[0];
  const void*  ei  = d_in[1];
  const float* W1  = (const float*)d_in[2];
  const float* b1  = (const float*)d_in[3];
  const float* Wg0 = (const float*)d_in[4];
  const float* bg0 = (const float*)d_in[5];
  const float* Wg1 = (const float*)d_in[6];
  const float* bg1 = (const float*)d_in[7];
  const float* W2  = (const float*)d_in[8];
  const float* b2  = (const float*)d_in[9];
  float* out = (float*)d_out;

  const int N = in_sizes[0] / 512;
  const int E = in_sizes[1] / 2;

  char* wsb = (char*)d_ws;
  size_t o = 0;
  auto alloc = [&](size_t bytes) -> void* {
    void* p = wsb + o;
    o = align_up(o + bytes, 256);
    return p;
  };
  int*    flag    = (int*)alloc(4);
  int*    src32   = (int*)alloc((size_t)E * 4);
  int*    dst32   = (int*)alloc((size_t)E * 4);
  float*  normv   = (float*)alloc((size_t)E * 4);
  int*    cnt     = (int*)alloc((size_t)N * 4);
  float*  dinv    = (float*)alloc((size_t)N * 4);
  int*    off     = (int*)alloc((size_t)(N + 1) * 4);
  int*    cursor  = (int*)alloc((size_t)N * 4);
  int*    bsum    = (int*)alloc(128 * 4);
  int*    boff    = (int*)alloc(128 * 4);
  int*    csr_src = (int*)alloc((size_t)E * 4);
  float*  csr_nrm = (float*)alloc((size_t)E * 4);
  ushort* W1t     = (ushort*)alloc((size_t)128 * 512 * 2);
  ushort* Wg0t    = (ushort*)alloc((size_t)128 * 128 * 2);
  ushort* Wg1t    = (ushort*)alloc((size_t)128 * 128 * 2);
  float*  bufA    = (float*)alloc((size_t)N * HID * 4);
  ushort* hwb     = (ushort*)alloc((size_t)N * HID * 2);
  (void)ws_size; (void)n_in; (void)out_size;

  const int tpb = 256;
  const int ebl = (E + tpb - 1) / tpb;
  const int nbl = (N + tpb - 1) / tpb;

  // --- graph prep ---
  detect_i64_kernel<<<1, 256, 0, stream>>>((const unsigned int*)ei, 2 * E, flag);
  extract_kernel<<<ebl, tpb, 0, stream>>>(ei, flag, E, src32, dst32);
  hipMemsetAsync(cnt, 0, (size_t)N * 4, stream);
  count_kernel<<<ebl, tpb, 0, stream>>>(dst32, cnt, E);
  dinv_kernel<<<nbl, tpb, 0, stream>>>(cnt, dinv, N);
  norm_kernel<<<ebl, tpb, 0, stream>>>(src32, dst32, dinv, normv, E);
  const int nsb = (N + 1023) / 1024;
  scan_local_kernel<<<nsb, 1024, 0, stream>>>(cnt, off, bsum, N);
  scan_bsum_kernel<<<1, 128, 0, stream>>>(bsum, nsb, boff, off + N);
  scan_add_kernel<<<nbl, tpb, 0, stream>>>(off, boff, cursor, N);
  fill_kernel<<<ebl, tpb, 0, stream>>>(src32, dst32, normv, cursor, csr_src, csr_nrm, E);

  // --- weight prep ---
  convert_w_kernel<<<(512 * 128 + 255) / 256, 256, 0, stream>>>(W1, W1t, 512);
  convert_w_kernel<<<(128 * 128 + 255) / 256, 256, 0, stream>>>(Wg0, Wg0t, 128);
  convert_w_kernel<<<(128 * 128 + 255) / 256, 256, 0, stream>>>(Wg1, Wg1t, 128);

  // --- network ---
  const int gbl = (N + 63) / 64;
  const int abl = (N * 64 + tpb - 1) / tpb;

  gemm_mfma_kernel<512, true><<<gbl, 256, 0, stream>>>(x, W1t, b1, bufA, N);

  gemm_mfma_kernel<128, false><<<gbl, 256, 0, stream>>>(bufA, Wg0t, nullptr, hwb, N);
  aggregate_bf16_kernel<<<abl, tpb, 0, stream>>>(hwb, off, csr_src, csr_nrm, dinv, bg0, bufA, N);

  gemm_mfma_kernel<128, false><<<gbl, 256, 0, stream>>>(bufA, Wg1t, nullptr, hwb, N);
  aggregate_bf16_kernel<<<abl, tpb, 0, stream>>>(hwb, off, csr_src, csr_nrm, dinv, bg1, bufA, N);

  final_kernel<<<abl, tpb, 0, stream>>>(bufA, W2, b2, out, N);
}

// Round 4
// 727.447 us; speedup vs baseline: 1.4159x; 1.1273x over previous
//
#include <hip/hip_runtime.h>
#include <hip/hip_bf16.h>
#include <cstdint>

#define HID 128

typedef short s16x8 __attribute__((ext_vector_type(8)));
typedef float f32x4 __attribute__((ext_vector_type(4)));

static inline size_t align_up(size_t x, size_t a) { return (x + a - 1) & ~(a - 1); }

__device__ inline ushort f2bf(float f) {
  uint u = __float_as_uint(f);
  u += 0x7FFFu + ((u >> 16) & 1u);
  return (ushort)(u >> 16);
}
__device__ inline float bf2f_lo(uint v) { return __uint_as_float(v << 16); }
__device__ inline float bf2f_hi(uint v) { return __uint_as_float(v & 0xFFFF0000u); }

// ---------------------------------------------------------------------------
// Edge dtype sniffer: int64 edge data with values < 2^31 has all odd 32-bit
// words == 0.
// ---------------------------------------------------------------------------
__global__ void detect_i64_kernel(const unsigned int* __restrict__ p, int nwords,
                                  int* __restrict__ flag) {
  __shared__ int any;
  if (threadIdx.x == 0) any = 0;
  __syncthreads();
  for (int i = threadIdx.x; i < 1024; i += blockDim.x) {
    int w = 2 * i + 1;
    if (w < nwords && p[w] != 0u) atomicOr(&any, 1);
  }
  __syncthreads();
  if (threadIdx.x == 0) *flag = (any == 0) ? 1 : 0;
}

__global__ void extract_kernel(const void* __restrict__ ei, const int* __restrict__ flag,
                               int E, int* __restrict__ src32, int* __restrict__ dst32) {
  int e = blockIdx.x * blockDim.x + threadIdx.x;
  if (e >= E) return;
  if (*flag) {
    const long long* p = (const long long*)ei;
    src32[e] = (int)p[e];
    dst32[e] = (int)p[(size_t)E + e];
  } else {
    const int* p = (const int*)ei;
    src32[e] = p[e];
    dst32[e] = p[(size_t)E + e];
  }
}

__global__ void count_kernel(const int* __restrict__ dst32, int* __restrict__ cnt, int E) {
  int e = blockIdx.x * blockDim.x + threadIdx.x;
  if (e >= E) return;
  atomicAdd(&cnt[dst32[e]], 1);
}

__global__ void dinv_kernel(const int* __restrict__ cnt, float* __restrict__ dinv, int N) {
  int i = blockIdx.x * blockDim.x + threadIdx.x;
  if (i >= N) return;
  dinv[i] = rsqrtf((float)(cnt[i] + 1));  // +1 self-loop
}

// ---------------------------------------------------------------------------
// Two-level exclusive scan over per-node counts -> CSR row offsets.
// ---------------------------------------------------------------------------
__global__ __launch_bounds__(1024) void scan_local_kernel(const int* __restrict__ cnt,
    int* __restrict__ off, int* __restrict__ bsum, int N) {
  __shared__ int buf[1024];
  int tid = threadIdx.x;
  int i = blockIdx.x * 1024 + tid;
  int v = (i < N) ? cnt[i] : 0;
  buf[tid] = v;
  __syncthreads();
  #pragma unroll
  for (int s = 1; s < 1024; s <<= 1) {
    int t = (tid >= s) ? buf[tid - s] : 0;
    __syncthreads();
    buf[tid] += t;
    __syncthreads();
  }
  if (i < N) off[i] = buf[tid] - v;
  if (tid == 1023) bsum[blockIdx.x] = buf[1023];
}

__global__ __launch_bounds__(128) void scan_bsum_kernel(const int* __restrict__ bsum, int nb,
    int* __restrict__ boff, int* __restrict__ offN) {
  __shared__ int b[128];
  int tid = threadIdx.x;
  int v = (tid < nb) ? bsum[tid] : 0;
  b[tid] = v;
  __syncthreads();
  #pragma unroll
  for (int s = 1; s < 128; s <<= 1) {
    int t = (tid >= s) ? b[tid - s] : 0;
    __syncthreads();
    b[tid] += t;
    __syncthreads();
  }
  if (tid < nb) boff[tid] = b[tid] - v;
  if (tid == 127) *offN = b[127];
}

__global__ void scan_add_kernel(int* __restrict__ off, const int* __restrict__ boff,
                                int* __restrict__ cursor, int N) {
  int i = blockIdx.x * blockDim.x + threadIdx.x;
  if (i >= N) return;
  int o = off[i] + boff[i >> 10];
  off[i] = o;
  cursor[i] = o;
}

// fill now computes norm on the fly (norm_kernel folded in)
__global__ void fill_kernel(const int* __restrict__ src32, const int* __restrict__ dst32,
                            const float* __restrict__ dinv, int* __restrict__ cursor,
                            int* __restrict__ csr_src, float* __restrict__ csr_norm, int E) {
  int e = blockIdx.x * blockDim.x + threadIdx.x;
  if (e >= E) return;
  int s = src32[e];
  int d = dst32[e];
  int pos = atomicAdd(&cursor[d], 1);
  csr_src[pos] = s;
  csr_norm[pos] = dinv[s] * dinv[d];
}

// ---------------------------------------------------------------------------
// Weight transpose + bf16 convert: W[K][128] f32 -> Wt[128][K] bf16.
// ---------------------------------------------------------------------------
__global__ void convert_w_kernel(const float* __restrict__ W, ushort* __restrict__ Wt, int K) {
  int id = blockIdx.x * blockDim.x + threadIdx.x;
  if (id >= K * 128) return;
  int c = id & 127;
  int k = id >> 7;
  Wt[(size_t)c * K + k] = f2bf(W[id]);
}

// W2[128][40] f32 -> W2t[48][128] bf16 (cols 40..47 zero-padded)
__global__ void convert_w2_kernel(const float* __restrict__ W2, ushort* __restrict__ Wt) {
  int id = blockIdx.x * blockDim.x + threadIdx.x;
  if (id >= 48 * 128) return;
  int c = id >> 7;
  int k = id & 127;
  Wt[(size_t)c * 128 + k] = (c < 40) ? f2bf(W2[(size_t)k * 40 + c]) : (ushort)0;
}

// ---------------------------------------------------------------------------
// LDS-free direct MFMA GEMM: out[M,128](bf16) = A[M,K] @ W (Wt[128][K] bf16).
// 4 waves/block, wave w owns a 16-row strip. Fragments loaded straight from
// global: A lane(l15,kg) = row base+l15, k kg*8.. (16B dwordx4, full 64B-line
// use); B frags from Wt (L1/L2-resident). No LDS, no barriers.
// C/D: col=lane&15, row=(lane>>4)*4+reg (verified r3).
// ---------------------------------------------------------------------------
template <int K, bool AF32, bool BIAS_RELU>
__global__ __launch_bounds__(256) void gemm_direct_kernel(const void* __restrict__ Ap,
    const ushort* __restrict__ Wt, const float* __restrict__ bias,
    ushort* __restrict__ outp, int M) {
  const int tid = threadIdx.x;
  const int w = tid >> 6;
  const int l = tid & 63;
  const int l15 = l & 15;
  const int kg = l >> 4;
  const int base = (blockIdx.x * 4 + w) * 16;
  if (base >= M) return;
  int row = base + l15;
  if (row >= M) row = M - 1;  // clamp loads; stores guarded below

  f32x4 acc[8];
  #pragma unroll
  for (int c = 0; c < 8; ++c) acc[c] = f32x4{0.f, 0.f, 0.f, 0.f};

  const ushort* Ab = (const ushort*)Ap;
  const float* Af = (const float*)Ap;

  for (int k0 = 0; k0 < K; k0 += 32) {
    s16x8 af;
    if constexpr (AF32) {
      const float* s = &Af[(size_t)row * K + k0 + kg * 8];
      float4 v0 = *(const float4*)s;
      float4 v1 = *(const float4*)(s + 4);
      af[0] = (short)f2bf(v0.x); af[1] = (short)f2bf(v0.y);
      af[2] = (short)f2bf(v0.z); af[3] = (short)f2bf(v0.w);
      af[4] = (short)f2bf(v1.x); af[5] = (short)f2bf(v1.y);
      af[6] = (short)f2bf(v1.z); af[7] = (short)f2bf(v1.w);
    } else {
      af = *(const s16x8*)&Ab[(size_t)row * K + k0 + kg * 8];
    }
    #pragma unroll
    for (int c = 0; c < 8; ++c) {
      s16x8 bfr = *(const s16x8*)&Wt[(size_t)(16 * c + l15) * K + k0 + kg * 8];
      acc[c] = __builtin_amdgcn_mfma_f32_16x16x32_bf16(af, bfr, acc[c], 0, 0, 0);
    }
  }

  #pragma unroll
  for (int c = 0; c < 8; ++c) {
    float b = 0.f;
    if constexpr (BIAS_RELU) b = bias[16 * c + l15];
    #pragma unroll
    for (int v = 0; v < 4; ++v) {
      int r = base + kg * 4 + v;
      if (r < M) {
        float val = acc[c][v];
        if constexpr (BIAS_RELU) val = fmaxf(val + b, 0.f);
        outp[(size_t)r * 128 + 16 * c + l15] = f2bf(val);
      }
    }
  }
}

// ---------------------------------------------------------------------------
// Aggregation over bf16 hw: one wave per node; lane l covers cols 2l,2l+1.
// f32 accumulate; self-loop + bias + ReLU; bf16 output (packed dword store).
// ---------------------------------------------------------------------------
__global__ __launch_bounds__(256) void aggregate_bf16_kernel(const ushort* __restrict__ hw,
    const int* __restrict__ off, const int* __restrict__ csr_src,
    const float* __restrict__ csr_norm, const float* __restrict__ dinv,
    const float* __restrict__ bias, ushort* __restrict__ out, int N) {
  int wid = (blockIdx.x * blockDim.x + threadIdx.x) >> 6;
  int lane = threadIdx.x & 63;
  if (wid >= N) return;
  const uint* hw4 = (const uint*)hw;
  int beg = off[wid], end = off[wid + 1];
  float ax = 0.f, ay = 0.f;
  for (int j = beg; j < end; ++j) {
    int s = csr_src[j];
    float nm = csr_norm[j];
    uint v = hw4[(size_t)s * 64 + lane];
    ax = fmaf(nm, bf2f_lo(v), ax);
    ay = fmaf(nm, bf2f_hi(v), ay);
  }
  float di = dinv[wid];
  float snm = di * di;
  uint v = hw4[(size_t)wid * 64 + lane];
  ax = fmaf(snm, bf2f_lo(v), ax);
  ay = fmaf(snm, bf2f_hi(v), ay);
  float2 b = ((const float2*)bias)[lane];
  float ox = fmaxf(ax + b.x, 0.f);
  float oy = fmaxf(ay + b.y, 0.f);
  ((uint*)out)[(size_t)wid * 64 + lane] = (uint)f2bf(ox) | ((uint)f2bf(oy) << 16);
}

// ---------------------------------------------------------------------------
// Final: logits = h @ W2 + b2 (MFMA, 48-col padded) ; log_softmax epilogue.
// Wave strip of 16 rows; lane group (kg) holds rows kg*4+v; softmax reduces
// across the 16 l15 lanes via shfl_xor(8,4,2,1) — stays in-group.
// ---------------------------------------------------------------------------
__global__ __launch_bounds__(256) void final_mfma_kernel(const ushort* __restrict__ h,
    const ushort* __restrict__ W2t, const float* __restrict__ b2,
    float* __restrict__ out, int M) {
  const int tid = threadIdx.x;
  const int w = tid >> 6;
  const int l = tid & 63;
  const int l15 = l & 15;
  const int kg = l >> 4;
  const int base = (blockIdx.x * 4 + w) * 16;
  if (base >= M) return;
  int row = base + l15;
  if (row >= M) row = M - 1;

  f32x4 acc[3];
  #pragma unroll
  for (int c = 0; c < 3; ++c) acc[c] = f32x4{0.f, 0.f, 0.f, 0.f};

  #pragma unroll
  for (int k0 = 0; k0 < 128; k0 += 32) {
    s16x8 af = *(const s16x8*)&h[(size_t)row * 128 + k0 + kg * 8];
    #pragma unroll
    for (int c = 0; c < 3; ++c) {
      s16x8 bfr = *(const s16x8*)&W2t[(size_t)(16 * c + l15) * 128 + k0 + kg * 8];
      acc[c] = __builtin_amdgcn_mfma_f32_16x16x32_bf16(af, bfr, acc[c], 0, 0, 0);
    }
  }

  float bv0 = b2[l15];
  float bv1 = b2[16 + l15];
  float bv2 = (l15 < 8) ? b2[32 + l15] : 0.f;

  #pragma unroll
  for (int v = 0; v < 4; ++v) {
    float l0 = acc[0][v] + bv0;
    float l1 = acc[1][v] + bv1;
    float l2 = (l15 < 8) ? (acc[2][v] + bv2) : -1e30f;
    float pm = fmaxf(fmaxf(l0, l1), l2);
    #pragma unroll
    for (int sh = 8; sh > 0; sh >>= 1) pm = fmaxf(pm, __shfl_xor(pm, sh));
    float es = expf(l0 - pm) + expf(l1 - pm) + ((l15 < 8) ? expf(l2 - pm) : 0.f);
    #pragma unroll
    for (int sh = 8; sh > 0; sh >>= 1) es += __shfl_xor(es, sh);
    float lse = pm + logf(es);
    int r = base + kg * 4 + v;
    if (r < M) {
      out[(size_t)r * 40 + l15] = l0 - lse;
      out[(size_t)r * 40 + 16 + l15] = l1 - lse;
      if (l15 < 8) out[(size_t)r * 40 + 32 + l15] = l2 - lse;
    }
  }
}

// ---------------------------------------------------------------------------
extern "C" void kernel_launch(void* const* d_in, const int* in_sizes, int n_in,
                              void* d_out, int out_size, void* d_ws, size_t ws_size,
                              hipStream_t stream) {
  const float* x   = (const float*)d_in[0];
  const void*  ei  = d_in[1];
  const float* W1  = (const float*)d_in[2];
  const float* b1  = (const float*)d_in[3];
  const float* Wg0 = (const float*)d_in[4];
  const float* bg0 = (const float*)d_in[5];
  const float* Wg1 = (const float*)d_in[6];
  const float* bg1 = (const float*)d_in[7];
  const float* W2  = (const float*)d_in[8];
  const float* b2  = (const float*)d_in[9];
  float* out = (float*)d_out;

  const int N = in_sizes[0] / 512;
  const int E = in_sizes[1] / 2;

  char* wsb = (char*)d_ws;
  size_t o = 0;
  auto alloc = [&](size_t bytes) -> void* {
    void* p = wsb + o;
    o = align_up(o + bytes, 256);
    return p;
  };
  int*    flag    = (int*)alloc(4);
  int*    src32   = (int*)alloc((size_t)E * 4);
  int*    dst32   = (int*)alloc((size_t)E * 4);
  int*    cnt     = (int*)alloc((size_t)N * 4);
  float*  dinv    = (float*)alloc((size_t)N * 4);
  int*    off     = (int*)alloc((size_t)(N + 1) * 4);
  int*    cursor  = (int*)alloc((size_t)N * 4);
  int*    bsum    = (int*)alloc(128 * 4);
  int*    boff    = (int*)alloc(128 * 4);
  int*    csr_src = (int*)alloc((size_t)E * 4);
  float*  csr_nrm = (float*)alloc((size_t)E * 4);
  ushort* W1t     = (ushort*)alloc((size_t)128 * 512 * 2);
  ushort* Wg0t    = (ushort*)alloc((size_t)128 * 128 * 2);
  ushort* Wg1t    = (ushort*)alloc((size_t)128 * 128 * 2);
  ushort* W2t     = (ushort*)alloc((size_t)48 * 128 * 2);
  ushort* hb1     = (ushort*)alloc((size_t)N * HID * 2);
  ushort* hb2     = (ushort*)alloc((size_t)N * HID * 2);
  (void)ws_size; (void)n_in; (void)out_size;

  const int tpb = 256;
  const int ebl = (E + tpb - 1) / tpb;
  const int nbl = (N + tpb - 1) / tpb;

  // --- graph prep ---
  detect_i64_kernel<<<1, 256, 0, stream>>>((const unsigned int*)ei, 2 * E, flag);
  extract_kernel<<<ebl, tpb, 0, stream>>>(ei, flag, E, src32, dst32);
  hipMemsetAsync(cnt, 0, (size_t)N * 4, stream);
  count_kernel<<<ebl, tpb, 0, stream>>>(dst32, cnt, E);
  dinv_kernel<<<nbl, tpb, 0, stream>>>(cnt, dinv, N);
  const int nsb = (N + 1023) / 1024;
  scan_local_kernel<<<nsb, 1024, 0, stream>>>(cnt, off, bsum, N);
  scan_bsum_kernel<<<1, 128, 0, stream>>>(bsum, nsb, boff, off + N);
  scan_add_kernel<<<nbl, tpb, 0, stream>>>(off, boff, cursor, N);
  fill_kernel<<<ebl, tpb, 0, stream>>>(src32, dst32, dinv, cursor, csr_src, csr_nrm, E);

  // --- weight prep ---
  convert_w_kernel<<<(512 * 128 + 255) / 256, 256, 0, stream>>>(W1, W1t, 512);
  convert_w_kernel<<<(128 * 128 + 255) / 256, 256, 0, stream>>>(Wg0, Wg0t, 128);
  convert_w_kernel<<<(128 * 128 + 255) / 256, 256, 0, stream>>>(Wg1, Wg1t, 128);
  convert_w2_kernel<<<(48 * 128 + 255) / 256, 256, 0, stream>>>(W2, W2t);

  // --- network ---
  const int gbl = (N + 63) / 64;
  const int abl = (N * 64 + tpb - 1) / tpb;

  gemm_direct_kernel<512, true, true><<<gbl, 256, 0, stream>>>(x, W1t, b1, hb1, N);

  gemm_direct_kernel<128, false, false><<<gbl, 256, 0, stream>>>(hb1, Wg0t, nullptr, hb2, N);
  aggregate_bf16_kernel<<<abl, tpb, 0, stream>>>(hb2, off, csr_src, csr_nrm, dinv, bg0, hb1, N);

  gemm_direct_kernel<128, false, false><<<gbl, 256, 0, stream>>>(hb1, Wg1t, nullptr, hb2, N);
  aggregate_bf16_kernel<<<abl, tpb, 0, stream>>>(hb2, off, csr_src, csr_nrm, dinv, bg1, hb1, N);

  final_mfma_kernel<<<gbl, 256, 0, stream>>>(hb1, W2t, b2, out, N);
}

// Round 5
// 650.223 us; speedup vs baseline: 1.5841x; 1.1188x over previous
//
#include <hip/hip_runtime.h>
#include <hip/hip_bf16.h>
#include <cstdint>

#define HID 128

typedef short s16x8 __attribute__((ext_vector_type(8)));
typedef float f32x4 __attribute__((ext_vector_type(4)));

static inline size_t align_up(size_t x, size_t a) { return (x + a - 1) & ~(a - 1); }

__device__ inline ushort f2bf(float f) {
  uint u = __float_as_uint(f);
  u += 0x7FFFu + ((u >> 16) & 1u);
  return (ushort)(u >> 16);
}
__device__ inline float bf2f_lo(uint v) { return __uint_as_float(v << 16); }
__device__ inline float bf2f_hi(uint v) { return __uint_as_float(v & 0xFFFF0000u); }

// ---------------------------------------------------------------------------
// Edge dtype sniffer: int64 edge data with values < 2^31 has all odd 32-bit
// words == 0.
// ---------------------------------------------------------------------------
__global__ void detect_i64_kernel(const unsigned int* __restrict__ p, int nwords,
                                  int* __restrict__ flag) {
  __shared__ int any;
  if (threadIdx.x == 0) any = 0;
  __syncthreads();
  for (int i = threadIdx.x; i < 1024; i += blockDim.x) {
    int w = 2 * i + 1;
    if (w < nwords && p[w] != 0u) atomicOr(&any, 1);
  }
  __syncthreads();
  if (threadIdx.x == 0) *flag = (any == 0) ? 1 : 0;
}

__global__ void extract_kernel(const void* __restrict__ ei, const int* __restrict__ flag,
                               int E, int* __restrict__ src32, int* __restrict__ dst32) {
  int e = blockIdx.x * blockDim.x + threadIdx.x;
  if (e >= E) return;
  if (*flag) {
    const long long* p = (const long long*)ei;
    src32[e] = (int)p[e];
    dst32[e] = (int)p[(size_t)E + e];
  } else {
    const int* p = (const int*)ei;
    src32[e] = p[e];
    dst32[e] = p[(size_t)E + e];
  }
}

__global__ void count_kernel(const int* __restrict__ dst32, int* __restrict__ cnt, int E) {
  int e = blockIdx.x * blockDim.x + threadIdx.x;
  if (e >= E) return;
  atomicAdd(&cnt[dst32[e]], 1);
}

__global__ void dinv_kernel(const int* __restrict__ cnt, float* __restrict__ dinv, int N) {
  int i = blockIdx.x * blockDim.x + threadIdx.x;
  if (i >= N) return;
  dinv[i] = rsqrtf((float)(cnt[i] + 1));  // +1 self-loop
}

// ---------------------------------------------------------------------------
// Two-level exclusive scan over per-node counts -> CSR row offsets.
// ---------------------------------------------------------------------------
__global__ __launch_bounds__(1024) void scan_local_kernel(const int* __restrict__ cnt,
    int* __restrict__ off, int* __restrict__ bsum, int N) {
  __shared__ int buf[1024];
  int tid = threadIdx.x;
  int i = blockIdx.x * 1024 + tid;
  int v = (i < N) ? cnt[i] : 0;
  buf[tid] = v;
  __syncthreads();
  #pragma unroll
  for (int s = 1; s < 1024; s <<= 1) {
    int t = (tid >= s) ? buf[tid - s] : 0;
    __syncthreads();
    buf[tid] += t;
    __syncthreads();
  }
  if (i < N) off[i] = buf[tid] - v;
  if (tid == 1023) bsum[blockIdx.x] = buf[1023];
}

__global__ __launch_bounds__(128) void scan_bsum_kernel(const int* __restrict__ bsum, int nb,
    int* __restrict__ boff, int* __restrict__ offN) {
  __shared__ int b[128];
  int tid = threadIdx.x;
  int v = (tid < nb) ? bsum[tid] : 0;
  b[tid] = v;
  __syncthreads();
  #pragma unroll
  for (int s = 1; s < 128; s <<= 1) {
    int t = (tid >= s) ? b[tid - s] : 0;
    __syncthreads();
    b[tid] += t;
    __syncthreads();
  }
  if (tid < nb) boff[tid] = b[tid] - v;
  if (tid == 127) *offN = b[127];
}

__global__ void scan_add_kernel(int* __restrict__ off, const int* __restrict__ boff,
                                int* __restrict__ cursor, int N) {
  int i = blockIdx.x * blockDim.x + threadIdx.x;
  if (i >= N) return;
  int o = off[i] + boff[i >> 10];
  off[i] = o;
  cursor[i] = o;
}

__global__ void fill_kernel(const int* __restrict__ src32, const int* __restrict__ dst32,
                            const float* __restrict__ dinv, int* __restrict__ cursor,
                            int* __restrict__ csr_src, float* __restrict__ csr_norm, int E) {
  int e = blockIdx.x * blockDim.x + threadIdx.x;
  if (e >= E) return;
  int s = src32[e];
  int d = dst32[e];
  int pos = atomicAdd(&cursor[d], 1);
  csr_src[pos] = s;
  csr_norm[pos] = dinv[s] * dinv[d];
}

// ---------------------------------------------------------------------------
// Weight transpose + bf16 convert: W[K][128] f32 -> Wt[128][K+8] bf16 (padded
// row stride; pad region never consumed).
// ---------------------------------------------------------------------------
__global__ void convert_w_kernel(const float* __restrict__ W, ushort* __restrict__ Wt,
                                 int K, int KP) {
  int id = blockIdx.x * blockDim.x + threadIdx.x;
  if (id >= K * 128) return;
  int c = id & 127;
  int k = id >> 7;
  Wt[(size_t)c * KP + k] = f2bf(W[id]);
}

// W2[128][40] f32 -> W2t[48][128] bf16 (cols 40..47 zero-padded)
__global__ void convert_w2_kernel(const float* __restrict__ W2, ushort* __restrict__ Wt) {
  int id = blockIdx.x * blockDim.x + threadIdx.x;
  if (id >= 48 * 128) return;
  int c = id >> 7;
  int k = id & 127;
  Wt[(size_t)c * 128 + k] = (c < 40) ? f2bf(W2[(size_t)k * 40 + c]) : (ushort)0;
}

// ---------------------------------------------------------------------------
// B-in-LDS MFMA GEMM: out[M,128](bf16) = A[M,K] @ W.
// Block stages the WHOLE Wt[128][K+8] into LDS once (K=512: 130 KB dynamic
// LDS, 1 block/CU; K=128: 34 KB, 4 blocks/CU), then WAVES waves sweep 16-row
// strips. A frags stream from HBM (coalesced dwordx4); B frags are
// ds_read_b128 at pad-8 stride (row shift = 4 banks -> uniform 32-bank
// coverage = b128 floor). No per-K-step global B loads -> latency off the
// critical path.
// C/D: col=lane&15, row=(lane>>4)*4+reg (verified r3).
// ---------------------------------------------------------------------------
template <int K, bool AF32, bool BIAS_RELU, int WAVES>
__global__ __launch_bounds__(WAVES * 64, 16 / WAVES) void gemm_lds_kernel(
    const void* __restrict__ Ap, const ushort* __restrict__ Wtp,
    const float* __restrict__ bias, ushort* __restrict__ outp,
    int M, int rowsPerBlock) {
  constexpr int KP = K + 8;
  extern __shared__ __align__(16) ushort lB[];  // 128*KP
  const int tid = threadIdx.x;

  const int rowStart = blockIdx.x * rowsPerBlock;
  if (rowStart >= M) return;
  const int rowEnd = min(M, rowStart + rowsPerBlock);

  // --- stage Wt -> LDS (linear 16B chunks, conflict-free) ---
  constexpr int TOTC = 128 * KP / 8;
  const s16x8* Wt8 = (const s16x8*)Wtp;
  for (int i = tid; i < TOTC; i += WAVES * 64) ((s16x8*)lB)[i] = Wt8[i];
  __syncthreads();

  const int w = tid >> 6;
  const int l = tid & 63;
  const int l15 = l & 15;
  const int kg = l >> 4;

  const ushort* Ab = (const ushort*)Ap;
  const float* Af = (const float*)Ap;

  for (int base = rowStart + w * 16; base < rowEnd; base += WAVES * 16) {
    int row = base + l15;
    if (row >= M) row = M - 1;  // clamp loads; stores guarded below

    f32x4 acc[8];
    #pragma unroll
    for (int c = 0; c < 8; ++c) acc[c] = f32x4{0.f, 0.f, 0.f, 0.f};

    #pragma unroll 4
    for (int k0 = 0; k0 < K; k0 += 32) {
      s16x8 af;
      if constexpr (AF32) {
        const float* s = &Af[(size_t)row * K + k0 + kg * 8];
        float4 v0 = *(const float4*)s;
        float4 v1 = *(const float4*)(s + 4);
        af[0] = (short)f2bf(v0.x); af[1] = (short)f2bf(v0.y);
        af[2] = (short)f2bf(v0.z); af[3] = (short)f2bf(v0.w);
        af[4] = (short)f2bf(v1.x); af[5] = (short)f2bf(v1.y);
        af[6] = (short)f2bf(v1.z); af[7] = (short)f2bf(v1.w);
      } else {
        af = *(const s16x8*)&Ab[(size_t)row * K + k0 + kg * 8];
      }
      #pragma unroll
      for (int c = 0; c < 8; ++c) {
        s16x8 bfr = *(const s16x8*)&lB[(16 * c + l15) * KP + k0 + kg * 8];
        acc[c] = __builtin_amdgcn_mfma_f32_16x16x32_bf16(af, bfr, acc[c], 0, 0, 0);
      }
    }

    #pragma unroll
    for (int c = 0; c < 8; ++c) {
      float b = 0.f;
      if constexpr (BIAS_RELU) b = bias[16 * c + l15];
      #pragma unroll
      for (int v = 0; v < 4; ++v) {
        int r = base + kg * 4 + v;
        if (r < M) {
          float val = acc[c][v];
          if constexpr (BIAS_RELU) val = fmaxf(val + b, 0.f);
          outp[(size_t)r * 128 + 16 * c + l15] = f2bf(val);
        }
      }
    }
  }
}

// ---------------------------------------------------------------------------
// Aggregation over bf16 hw: one wave per node; lane l covers cols 2l,2l+1.
// f32 accumulate; self-loop + bias + ReLU; bf16 output (packed dword store).
// ---------------------------------------------------------------------------
__global__ __launch_bounds__(256) void aggregate_bf16_kernel(const ushort* __restrict__ hw,
    const int* __restrict__ off, const int* __restrict__ csr_src,
    const float* __restrict__ csr_norm, const float* __restrict__ dinv,
    const float* __restrict__ bias, ushort* __restrict__ out, int N) {
  int wid = (blockIdx.x * blockDim.x + threadIdx.x) >> 6;
  int lane = threadIdx.x & 63;
  if (wid >= N) return;
  const uint* hw4 = (const uint*)hw;
  int beg = off[wid], end = off[wid + 1];
  float ax = 0.f, ay = 0.f;
  for (int j = beg; j < end; ++j) {
    int s = csr_src[j];
    float nm = csr_norm[j];
    uint v = hw4[(size_t)s * 64 + lane];
    ax = fmaf(nm, bf2f_lo(v), ax);
    ay = fmaf(nm, bf2f_hi(v), ay);
  }
  float di = dinv[wid];
  float snm = di * di;
  uint v = hw4[(size_t)wid * 64 + lane];
  ax = fmaf(snm, bf2f_lo(v), ax);
  ay = fmaf(snm, bf2f_hi(v), ay);
  float2 b = ((const float2*)bias)[lane];
  float ox = fmaxf(ax + b.x, 0.f);
  float oy = fmaxf(ay + b.y, 0.f);
  ((uint*)out)[(size_t)wid * 64 + lane] = (uint)f2bf(ox) | ((uint)f2bf(oy) << 16);
}

// ---------------------------------------------------------------------------
// Final: logits = h @ W2 + b2 (MFMA, 48-col padded) ; log_softmax epilogue.
// ---------------------------------------------------------------------------
__global__ __launch_bounds__(256) void final_mfma_kernel(const ushort* __restrict__ h,
    const ushort* __restrict__ W2t, const float* __restrict__ b2,
    float* __restrict__ out, int M) {
  const int tid = threadIdx.x;
  const int w = tid >> 6;
  const int l = tid & 63;
  const int l15 = l & 15;
  const int kg = l >> 4;
  const int base = (blockIdx.x * 4 + w) * 16;
  if (base >= M) return;
  int row = base + l15;
  if (row >= M) row = M - 1;

  f32x4 acc[3];
  #pragma unroll
  for (int c = 0; c < 3; ++c) acc[c] = f32x4{0.f, 0.f, 0.f, 0.f};

  #pragma unroll
  for (int k0 = 0; k0 < 128; k0 += 32) {
    s16x8 af = *(const s16x8*)&h[(size_t)row * 128 + k0 + kg * 8];
    #pragma unroll
    for (int c = 0; c < 3; ++c) {
      s16x8 bfr = *(const s16x8*)&W2t[(size_t)(16 * c + l15) * 128 + k0 + kg * 8];
      acc[c] = __builtin_amdgcn_mfma_f32_16x16x32_bf16(af, bfr, acc[c], 0, 0, 0);
    }
  }

  float bv0 = b2[l15];
  float bv1 = b2[16 + l15];
  float bv2 = (l15 < 8) ? b2[32 + l15] : 0.f;

  #pragma unroll
  for (int v = 0; v < 4; ++v) {
    float l0 = acc[0][v] + bv0;
    float l1 = acc[1][v] + bv1;
    float l2 = (l15 < 8) ? (acc[2][v] + bv2) : -1e30f;
    float pm = fmaxf(fmaxf(l0, l1), l2);
    #pragma unroll
    for (int sh = 8; sh > 0; sh >>= 1) pm = fmaxf(pm, __shfl_xor(pm, sh));
    float es = expf(l0 - pm) + expf(l1 - pm) + ((l15 < 8) ? expf(l2 - pm) : 0.f);
    #pragma unroll
    for (int sh = 8; sh > 0; sh >>= 1) es += __shfl_xor(es, sh);
    float lse = pm + logf(es);
    int r = base + kg * 4 + v;
    if (r < M) {
      out[(size_t)r * 40 + l15] = l0 - lse;
      out[(size_t)r * 40 + 16 + l15] = l1 - lse;
      if (l15 < 8) out[(size_t)r * 40 + 32 + l15] = l2 - lse;
    }
  }
}

// ---------------------------------------------------------------------------
extern "C" void kernel_launch(void* const* d_in, const int* in_sizes, int n_in,
                              void* d_out, int out_size, void* d_ws, size_t ws_size,
                              hipStream_t stream) {
  const float* x   = (const float*)d_in[0];
  const void*  ei  = d_in[1];
  const float* W1  = (const float*)d_in[2];
  const float* b1  = (const float*)d_in[3];
  const float* Wg0 = (const float*)d_in[4];
  const float* bg0 = (const float*)d_in[5];
  const float* Wg1 = (const float*)d_in[6];
  const float* bg1 = (const float*)d_in[7];
  const float* W2  = (const float*)d_in[8];
  const float* b2  = (const float*)d_in[9];
  float* out = (float*)d_out;

  const int N = in_sizes[0] / 512;
  const int E = in_sizes[1] / 2;

  char* wsb = (char*)d_ws;
  size_t o = 0;
  auto alloc = [&](size_t bytes) -> void* {
    void* p = wsb + o;
    o = align_up(o + bytes, 256);
    return p;
  };
  int*    flag    = (int*)alloc(4);
  int*    src32   = (int*)alloc((size_t)E * 4);
  int*    dst32   = (int*)alloc((size_t)E * 4);
  int*    cnt     = (int*)alloc((size_t)N * 4);
  float*  dinv    = (float*)alloc((size_t)N * 4);
  int*    off     = (int*)alloc((size_t)(N + 1) * 4);
  int*    cursor  = (int*)alloc((size_t)N * 4);
  int*    bsum    = (int*)alloc(128 * 4);
  int*    boff    = (int*)alloc(128 * 4);
  int*    csr_src = (int*)alloc((size_t)E * 4);
  float*  csr_nrm = (float*)alloc((size_t)E * 4);
  ushort* W1t     = (ushort*)alloc((size_t)128 * 520 * 2);
  ushort* Wg0t    = (ushort*)alloc((size_t)128 * 136 * 2);
  ushort* Wg1t    = (ushort*)alloc((size_t)128 * 136 * 2);
  ushort* W2t     = (ushort*)alloc((size_t)48 * 128 * 2);
  ushort* hb1     = (ushort*)alloc((size_t)N * HID * 2);
  ushort* hb2     = (ushort*)alloc((size_t)N * HID * 2);
  (void)ws_size; (void)n_in; (void)out_size;

  const int tpb = 256;
  const int ebl = (E + tpb - 1) / tpb;
  const int nbl = (N + tpb - 1) / tpb;

  // --- graph prep ---
  detect_i64_kernel<<<1, 256, 0, stream>>>((const unsigned int*)ei, 2 * E, flag);
  extract_kernel<<<ebl, tpb, 0, stream>>>(ei, flag, E, src32, dst32);
  hipMemsetAsync(cnt, 0, (size_t)N * 4, stream);
  count_kernel<<<ebl, tpb, 0, stream>>>(dst32, cnt, E);
  dinv_kernel<<<nbl, tpb, 0, stream>>>(cnt, dinv, N);
  const int nsb = (N + 1023) / 1024;
  scan_local_kernel<<<nsb, 1024, 0, stream>>>(cnt, off, bsum, N);
  scan_bsum_kernel<<<1, 128, 0, stream>>>(bsum, nsb, boff, off + N);
  scan_add_kernel<<<nbl, tpb, 0, stream>>>(off, boff, cursor, N);
  fill_kernel<<<ebl, tpb, 0, stream>>>(src32, dst32, dinv, cursor, csr_src, csr_nrm, E);

  // --- weight prep ---
  convert_w_kernel<<<(512 * 128 + 255) / 256, 256, 0, stream>>>(W1, W1t, 512, 520);
  convert_w_kernel<<<(128 * 128 + 255) / 256, 256, 0, stream>>>(Wg0, Wg0t, 128, 136);
  convert_w_kernel<<<(128 * 128 + 255) / 256, 256, 0, stream>>>(Wg1, Wg1t, 128, 136);
  convert_w2_kernel<<<(48 * 128 + 255) / 256, 256, 0, stream>>>(W2, W2t);

  // --- network ---
  // GEMM1: 130 KB dynamic LDS -> opt-in attribute (idempotent, capture-safe).
  const size_t lds512 = (size_t)128 * 520 * 2;
  const size_t lds128 = (size_t)128 * 136 * 2;
  static bool attr_done = false;
  if (!attr_done) {
    (void)hipFuncSetAttribute(
        reinterpret_cast<const void*>(&gemm_lds_kernel<512, true, true, 8>),
        hipFuncAttributeMaxDynamicSharedMemorySize, (int)lds512);
    attr_done = true;
  }

  int rpb512 = (N + 255) / 256;
  rpb512 = (rpb512 + 15) & ~15;
  const int grid512 = (N + rpb512 - 1) / rpb512;
  const int rpb128 = 128;
  const int grid128 = (N + rpb128 - 1) / rpb128;
  const int abl = (N * 64 + tpb - 1) / tpb;
  const int fbl = (N + 63) / 64;

  gemm_lds_kernel<512, true, true, 8><<<grid512, 512, lds512, stream>>>(
      x, W1t, b1, hb1, N, rpb512);

  gemm_lds_kernel<128, false, false, 4><<<grid128, 256, lds128, stream>>>(
      hb1, Wg0t, nullptr, hb2, N, rpb128);
  aggregate_bf16_kernel<<<abl, tpb, 0, stream>>>(hb2, off, csr_src, csr_nrm, dinv, bg0, hb1, N);

  gemm_lds_kernel<128, false, false, 4><<<grid128, 256, lds128, stream>>>(
      hb1, Wg1t, nullptr, hb2, N, rpb128);
  aggregate_bf16_kernel<<<abl, tpb, 0, stream>>>(hb2, off, csr_src, csr_nrm, dinv, bg1, hb1, N);

  final_mfma_kernel<<<fbl, 256, 0, stream>>>(hb1, W2t, b2, out, N);
}